// Round 9
// baseline (2629.202 us; speedup 1.0000x reference)
//
#include <hip/hip_runtime.h>
#include <hip/hip_bf16.h>

// ChebNet: N=100000, E=1600000, IN=HID=128, OUT=40, K=3, 5 hidden layers.
//  v7: - degree-sorted node permutation for spmm: waves process equal-degree
//        nodes -> no max-of-4 divergence waste, aligned tails. Exact reorder.
//      - activations fp16 in SCALED space Z = dinv .* Y (spmm = pure gather-sum).
//      - bucketed CSR build (dst>>6): LDS hist + packed scatter + counting sort.
//      - GEMM: bf16x3 split MFMA, W precomputed [ncol][k] hi/lo, LDS slab copy.

#define NN 100000
#define EE 1600000
#define FF 128
#define NBK 1563           // (NN+63)>>6
#define EPB 4096           // edges per block in bucket passes
#define CAP 3072           // per-bucket staging capacity

typedef __attribute__((ext_vector_type(8))) short short8_t;
typedef __attribute__((ext_vector_type(8))) _Float16 half8_t;
typedef __attribute__((ext_vector_type(4))) _Float16 half4_t;
typedef __attribute__((ext_vector_type(4))) float floatx4;
typedef __attribute__((ext_vector_type(4))) float accfrag;

// ---------------- bucketed CSR build ----------------

__global__ __launch_bounds__(256) void bhist_kernel(const int* __restrict__ dst,
                                                    int* __restrict__ bcnt) {
    __shared__ int lh[NBK];
    int tid = threadIdx.x;
    for (int j = tid; j < NBK; j += 256) lh[j] = 0;
    __syncthreads();
    int e0 = blockIdx.x * EPB;
#pragma unroll
    for (int k = 0; k < EPB / 256; ++k) {
        int i = e0 + k * 256 + tid;
        if (i < EE) atomicAdd(&lh[dst[i] >> 6], 1);
    }
    __syncthreads();
    for (int j = tid; j < NBK; j += 256)
        if (lh[j] > 0) atomicAdd(&bcnt[j], lh[j]);
}

__global__ __launch_bounds__(256) void scan_p1_kernel(const int* __restrict__ cnt,
                                                      int* __restrict__ bsum, int n) {
    __shared__ int red[8];
    int i = blockIdx.x * 256 + threadIdx.x;
    int v = (i < n) ? cnt[i] : 0;
    for (int off = 32; off > 0; off >>= 1) v += __shfl_down(v, off, 64);
    int wv = threadIdx.x >> 6;
    if ((threadIdx.x & 63) == 0) red[wv] = v;
    __syncthreads();
    if (threadIdx.x == 0) bsum[blockIdx.x] = red[0] + red[1] + red[2] + red[3];
}

__global__ __launch_bounds__(1024) void scan_p2_kernel(int* __restrict__ bsum, int nb) {
    __shared__ int s[1024];
    int tid = threadIdx.x;
    int v = (tid < nb) ? bsum[tid] : 0;
    s[tid] = v;
    __syncthreads();
    for (int off = 1; off < 1024; off <<= 1) {
        int u = (tid >= off) ? s[tid - off] : 0;
        __syncthreads();
        s[tid] += u;
        __syncthreads();
    }
    if (tid < nb) bsum[tid] = s[tid] - v;
}

__global__ __launch_bounds__(256) void scan_p3_kernel(const int* __restrict__ cnt,
                                                      const int* __restrict__ bsum,
                                                      int* __restrict__ out_ptr, int n) {
    __shared__ int s[256];
    int tid = threadIdx.x;
    int i = blockIdx.x * 256 + tid;
    int v = (i < n) ? cnt[i] : 0;
    s[tid] = v;
    __syncthreads();
    for (int off = 1; off < 256; off <<= 1) {
        int u = (tid >= off) ? s[tid - off] : 0;
        __syncthreads();
        s[tid] += u;
        __syncthreads();
    }
    if (i < n) {
        int excl = bsum[blockIdx.x] + s[tid] - v;
        out_ptr[i] = excl;
        if (i == n - 1) out_ptr[n] = excl + v;
    }
}

__global__ __launch_bounds__(256) void bscatter_kernel(
    const int* __restrict__ src, const int* __restrict__ dst,
    const int* __restrict__ bptr, int* __restrict__ bfill, int* __restrict__ ebuf) {
    __shared__ int lh[NBK];
    __shared__ int lbase[NBK];
    int tid = threadIdx.x;
    for (int j = tid; j < NBK; j += 256) lh[j] = 0;
    __syncthreads();
    int e0 = blockIdx.x * EPB;
#pragma unroll
    for (int k = 0; k < EPB / 256; ++k) {
        int i = e0 + k * 256 + tid;
        if (i < EE) atomicAdd(&lh[dst[i] >> 6], 1);
    }
    __syncthreads();
    for (int j = tid; j < NBK; j += 256)
        if (lh[j] > 0) lbase[j] = atomicAdd(&bfill[j], lh[j]);
    __syncthreads();
    for (int j = tid; j < NBK; j += 256) lh[j] = 0;
    __syncthreads();
#pragma unroll
    for (int k = 0; k < EPB / 256; ++k) {
        int i = e0 + k * 256 + tid;
        if (i < EE) {
            int d = dst[i];
            int b = d >> 6;
            int off = atomicAdd(&lh[b], 1);
            ebuf[bptr[b] + lbase[b] + off] = (src[i] << 6) | (d & 63);
        }
    }
}

__global__ __launch_bounds__(256) void csr_build_kernel(
    const int* __restrict__ ebuf, const int* __restrict__ bptr,
    int* __restrict__ rowptr, int* __restrict__ colsrc,
    float* __restrict__ dinv, float* __restrict__ dinv2, float* __restrict__ sdeg) {
    __shared__ int pk[CAP];
    __shared__ int ob[CAP];
    __shared__ int cnt[64];
    __shared__ int sexcl[64];
    __shared__ int fill[64];

    int tid = threadIdx.x;
    int b = blockIdx.x;
    int start = bptr[b];
    int cb = bptr[b + 1] - start;
    if (cb > CAP) cb = CAP;

    if (tid < 64) { cnt[tid] = 0; fill[tid] = 0; }
    __syncthreads();

    for (int i = tid; i < cb; i += 256) {
        int v = ebuf[start + i];
        pk[i] = v;
        atomicAdd(&cnt[v & 63], 1);
    }
    __syncthreads();

    if (tid < 64) {
        int v = cnt[tid];
        int inc = v;
        for (int off = 1; off < 64; off <<= 1) {
            int u = __shfl_up(inc, off, 64);
            if (tid >= off) inc += u;
        }
        int excl = inc - v;
        sexcl[tid] = excl;
        int gnode = b * 64 + tid;
        if (gnode < NN) {
            rowptr[gnode] = start + excl;
            int d = v < 1 ? 1 : v;
            float fd = (float)d;
            dinv[gnode]  = 1.0f / sqrtf(fd);
            dinv2[gnode] = 1.0f / fd;
            sdeg[gnode]  = sqrtf(fd);
        }
    }
    if (b == 0 && tid == 0) rowptr[NN] = EE;
    __syncthreads();

    for (int i = tid; i < cb; i += 256) {
        int v = pk[i];
        int d = v & 63;
        int off = atomicAdd(&fill[d], 1);
        ob[sexcl[d] + off] = v >> 6;
    }
    __syncthreads();

    for (int i = tid; i < cb; i += 256) colsrc[start + i] = ob[i];
}

// ---------------- degree-sorted permutation (counting sort, 64 bins) ----------------

__global__ __launch_bounds__(256) void dsort_p1_kernel(const int* __restrict__ rowptr,
                                                       int* __restrict__ dbins, int n) {
    __shared__ int lh[64];
    int tid = threadIdx.x;
    if (tid < 64) lh[tid] = 0;
    __syncthreads();
    int i = blockIdx.x * 256 + tid;
    if (i < n) {
        int d = rowptr[i + 1] - rowptr[i];
        if (d > 63) d = 63;
        atomicAdd(&lh[d], 1);
    }
    __syncthreads();
    if (tid < 64 && lh[tid] > 0) atomicAdd(&dbins[tid], lh[tid]);
}

__global__ __launch_bounds__(64) void dsort_p2_kernel(int* __restrict__ dbins) {
    int tid = threadIdx.x;
    int v = dbins[tid];
    int inc = v;
    for (int off = 1; off < 64; off <<= 1) {
        int u = __shfl_up(inc, off, 64);
        if (tid >= off) inc += u;
    }
    dbins[tid] = inc - v;   // exclusive base
}

__global__ __launch_bounds__(256) void dsort_p3_kernel(const int* __restrict__ rowptr,
                                                       const int* __restrict__ dbase,
                                                       int* __restrict__ dfill,
                                                       int* __restrict__ perm, int n) {
    int i = blockIdx.x * 256 + threadIdx.x;
    if (i >= n) return;
    int d = rowptr[i + 1] - rowptr[i];
    if (d > 63) d = 63;
    int pos = dbase[d] + atomicAdd(&dfill[d], 1);
    perm[pos] = i;
}

// ---------------- fp32 -> bf16 hi/lo split (round both) ----------------

__device__ inline void f2bf_hilo(float x, short* hi, short* lo) {
    union { float f; unsigned u; } a; a.f = x;
    unsigned uh = a.u + 0x7FFFu + ((a.u >> 16) & 1u);
    unsigned short h = (unsigned short)(uh >> 16);
    union { unsigned u; float f; } hf; hf.u = ((unsigned)h) << 16;
    float r = x - hf.f;
    union { float f; unsigned u; } b; b.f = r;
    unsigned ul = b.u + 0x7FFFu + ((b.u >> 16) & 1u);
    *hi = (short)h; *lo = (short)(ul >> 16);
}

__device__ inline void split8a(const float* f, short8_t* hi, short8_t* lo) {
    short h[8], l[8];
#pragma unroll
    for (int i = 0; i < 8; ++i) {
        union { float f; unsigned u; } x; x.f = f[i];
        unsigned hu = x.u & 0xFFFF0000u;
        h[i] = (short)(hu >> 16);
        union { unsigned u; float f; } hf; hf.u = hu;
        float r = f[i] - hf.f;
        union { float f; unsigned u; } rr; rr.f = r;
        unsigned ul = rr.u + 0x7FFFu + ((rr.u >> 16) & 1u);
        l[i] = (short)(ul >> 16);
    }
    *hi = (short8_t){ h[0], h[1], h[2], h[3], h[4], h[5], h[6], h[7] };
    *lo = (short8_t){ l[0], l[1], l[2], l[3], l[4], l[5], l[6], l[7] };
}

// ---------------- W precompute: [layer][ncol(128)][k(384)] hi/lo bf16 ----------------

__global__ __launch_bounds__(256) void wprep_kernel(
    const float* __restrict__ W0, const float* __restrict__ Wh, const float* __restrict__ Wl,
    short* __restrict__ Whi_t, short* __restrict__ Wlo_t)
{
    int idx = blockIdx.x * 256 + threadIdx.x;
    const int PER = 128 * 384;
    if (idx >= 7 * PER) return;
    int layer = idx / PER;
    int rem = idx - layer * PER;
    int ncol = rem / 384;
    int k = rem - ncol * 384;
    const float* W; int outc;
    if (layer == 0)      { W = W0; outc = 128; }
    else if (layer < 6)  { W = Wh + (size_t)(layer - 1) * 384 * 128; outc = 128; }
    else                 { W = Wl; outc = 40; }
    float v = (ncol < outc) ? W[(size_t)k * outc + ncol] : 0.f;
    short h, l;
    f2bf_hilo(v, &h, &l);
    Whi_t[idx] = h;
    Wlo_t[idx] = l;
}

// ---------------- feature convert: Z0 = dinv .* X, fp16 ----------------

__global__ __launch_bounds__(256) void fcvt_kernel(const float* __restrict__ in,
                                                   const float* __restrict__ dinv,
                                                   _Float16* __restrict__ out, int total4) {
    int i = blockIdx.x * 256 + threadIdx.x;
    if (i >= total4) return;
    int node = i >> 5;
    float dv = dinv[node];
    floatx4 v = *(const floatx4*)&in[i * 4];
    half4_t r = { (_Float16)(dv * v.x), (_Float16)(dv * v.y),
                  (_Float16)(dv * v.z), (_Float16)(dv * v.w) };
    *(half4_t*)&out[i * 4] = r;
}

// ---------------- SpMM (Z-space, pure gather-sum, degree-sorted) ----------------
// Zout[d] = alpha*dinv2[d]*sum_e Zin[src] + beta*Zo[d],  d = perm[g]

__global__ __launch_bounds__(256, 8) void spmm_h_kernel(
    _Float16* __restrict__ out, const _Float16* __restrict__ Xin,
    const _Float16* __restrict__ Xo, const float* __restrict__ dinv2,
    const int* __restrict__ rp, const int* __restrict__ cs,
    const int* __restrict__ perm, float alpha, float beta, int n)
{
    int slot = threadIdx.x >> 4;
    int lane = threadIdx.x & 15;
    int g = blockIdx.x * 16 + slot;
    if (g >= n) return;
    int node = perm[g];
    const half8_t* X8 = (const half8_t*)Xin;
    float acc[8] = { 0.f, 0.f, 0.f, 0.f, 0.f, 0.f, 0.f, 0.f };
    int s = rp[node], e = rp[node + 1];
    int i = s;
    for (; i + 8 <= e; i += 8) {
        int idx[8];
#pragma unroll
        for (int u = 0; u < 8; ++u) idx[u] = cs[i + u];
        half8_t x[8];
#pragma unroll
        for (int u = 0; u < 8; ++u) x[u] = X8[(size_t)idx[u] * 16 + lane];
#pragma unroll
        for (int u = 0; u < 8; ++u)
#pragma unroll
            for (int j = 0; j < 8; ++j) acc[j] += (float)x[u][j];
    }
    for (; i < e; ++i) {
        int sidx = cs[i];
        half8_t x = X8[(size_t)sidx * 16 + lane];
#pragma unroll
        for (int j = 0; j < 8; ++j) acc[j] += (float)x[j];
    }
    float sc = alpha * dinv2[node];
    half8_t r;
    if (beta != 0.f) {
        half8_t o = ((const half8_t*)Xo)[(size_t)node * 16 + lane];
#pragma unroll
        for (int j = 0; j < 8; ++j) r[j] = (_Float16)(sc * acc[j] + beta * (float)o[j]);
    } else {
#pragma unroll
        for (int j = 0; j < 8; ++j) r[j] = (_Float16)(sc * acc[j]);
    }
    ((half8_t*)out)[(size_t)node * 16 + lane] = r;
}

// ---------------- GEMM: LDS W-slab bf16x3 MFMA, Z-space A ----------------

template <int OUTC, int NT, bool HOUT>
__global__ __launch_bounds__(256, 2) void gemm_mfma5_kernel(
    void* __restrict__ outp, const _Float16* __restrict__ X0,
    const _Float16* __restrict__ X1, const _Float16* __restrict__ X2,
    const short* __restrict__ Whi_t, const short* __restrict__ Wlo_t,
    const float* __restrict__ bias, const float* __restrict__ sdeg,
    const float* __restrict__ dinv, int n)
{
    __shared__ short Ws[2][NT * 16][136];

    int tid = threadIdx.x;
    int lane = tid & 63;
    int wave = tid >> 6;
    int m15 = lane & 15;
    int quad = lane >> 4;
    int row0 = blockIdx.x * 128 + wave * 32;

    accfrag acc[2][NT];
#pragma unroll
    for (int mi = 0; mi < 2; ++mi)
#pragma unroll
        for (int nj = 0; nj < NT; ++nj) acc[mi][nj] = (accfrag){0.f, 0.f, 0.f, 0.f};

    int r0 = row0 + m15;
    int r1 = r0 + 16;
    float s0 = (r0 < n) ? sdeg[r0] : 0.f;
    float s1 = (r1 < n) ? sdeg[r1] : 0.f;
    size_t ro0 = (size_t)((r0 < n) ? r0 : 0) * 16;
    size_t ro1 = (size_t)((r1 < n) ? r1 : 0) * 16;

    const _Float16* srcs[3] = { X0, X1, X2 };

    for (int sb = 0; sb < 3; ++sb) {
        {
            const int VEC = NT * 512;
#pragma unroll
            for (int v0 = 0; v0 < VEC; v0 += 256) {
                int v = v0 + tid;
                int a = (v >= NT * 256) ? 1 : 0;
                int rem = v - a * (NT * 256);
                int row = rem >> 4;
                int c8 = (rem & 15) * 8;
                const short* g = (a ? Wlo_t : Whi_t) + (size_t)row * 384 + sb * 128 + c8;
                *(short8_t*)&Ws[a][row][c8] = *(const short8_t*)g;
            }
        }
        __syncthreads();

        const half8_t* Xp8 = (const half8_t*)srcs[sb];
#pragma unroll
        for (int kk = 0; kk < 4; ++kk) {
            int k0 = kk * 32 + quad * 8;
            half8_t h0 = Xp8[ro0 + kk * 4 + quad];
            half8_t h1 = Xp8[ro1 + kk * 4 + quad];
            float f0[8], f1[8];
#pragma unroll
            for (int j = 0; j < 8; ++j) { f0[j] = s0 * (float)h0[j]; f1[j] = s1 * (float)h1[j]; }
            short8_t a_hi[2], a_lo[2];
            split8a(f0, &a_hi[0], &a_lo[0]);
            split8a(f1, &a_hi[1], &a_lo[1]);

#pragma unroll
            for (int nj = 0; nj < NT; ++nj) {
                short8_t b_hi = *(const short8_t*)&Ws[0][nj * 16 + m15][k0];
                short8_t b_lo = *(const short8_t*)&Ws[1][nj * 16 + m15][k0];
#pragma unroll
                for (int mi = 0; mi < 2; ++mi) {
                    acc[mi][nj] = __builtin_amdgcn_mfma_f32_16x16x32_bf16(a_hi[mi], b_hi, acc[mi][nj], 0, 0, 0);
                    acc[mi][nj] = __builtin_amdgcn_mfma_f32_16x16x32_bf16(a_lo[mi], b_hi, acc[mi][nj], 0, 0, 0);
                    acc[mi][nj] = __builtin_amdgcn_mfma_f32_16x16x32_bf16(a_hi[mi], b_lo, acc[mi][nj], 0, 0, 0);
                }
            }
        }
        __syncthreads();
    }

    float dvs[2][4];
    if (HOUT) {
#pragma unroll
        for (int mi = 0; mi < 2; ++mi)
#pragma unroll
            for (int reg = 0; reg < 4; ++reg) {
                int gr = row0 + mi * 16 + quad * 4 + reg;
                dvs[mi][reg] = (gr < n) ? dinv[gr] : 0.f;
            }
    }
#pragma unroll
    for (int nj = 0; nj < NT; ++nj) {
        int col = nj * 16 + m15;
        float bv = (col < OUTC) ? bias[col] : 0.f;
#pragma unroll
        for (int mi = 0; mi < 2; ++mi) {
#pragma unroll
            for (int reg = 0; reg < 4; ++reg) {
                int gr = row0 + mi * 16 + quad * 4 + reg;
                if (gr < n && col < OUTC) {
                    float v = acc[mi][nj][reg] + bv;
                    v = v > 0.f ? v : 0.f;
                    if (HOUT) ((_Float16*)outp)[(size_t)gr * OUTC + col] = (_Float16)(v * dvs[mi][reg]);
                    else      ((float*)outp)[(size_t)gr * OUTC + col] = v;
                }
            }
        }
    }
}

// ---------------- launch ----------------

extern "C" void kernel_launch(void* const* d_in, const int* in_sizes, int n_in,
                              void* d_out, int out_size, void* d_ws, size_t ws_size,
                              hipStream_t stream) {
    const float* features = (const float*)d_in[0];
    const int*   src      = (const int*)d_in[1];
    const int*   dst      = (const int*)d_in[2];
    const float* W0       = (const float*)d_in[3];
    const float* b0       = (const float*)d_in[4];
    const float* Wh       = (const float*)d_in[5];
    const float* bh       = (const float*)d_in[6];
    const float* Wl       = (const float*)d_in[7];
    const float* bl       = (const float*)d_in[8];
    float* out = (float*)d_out;

    const int N = NN, E = EE;
    const int WTOT = 7 * 128 * 384;
    const int EB = (E + EPB - 1) / EPB;
    const int NB2 = (NBK + 255) / 256;

    char* ws = (char*)d_ws;
    size_t off = 0;
    auto alloc = [&](size_t bytes) -> void* {
        void* p = ws + off;
        off += (bytes + 511) & ~(size_t)511;
        return p;
    };
    int*      bcnt   = (int*)alloc((size_t)NBK * 4);
    int*      bfill  = (int*)alloc((size_t)NBK * 4);
    int*      bptr   = (int*)alloc((size_t)(NBK + 1) * 4);
    int*      bsum   = (int*)alloc((size_t)NB2 * 4);
    int*      rowptr = (int*)alloc((size_t)(N + 1) * 4);
    int*      ebuf   = (int*)alloc((size_t)E * 4);
    int*      colsrc = (int*)alloc((size_t)E * 4);
    float*    dinv   = (float*)alloc((size_t)N * 4);
    float*    dinv2  = (float*)alloc((size_t)N * 4);
    float*    sdeg   = (float*)alloc((size_t)N * 4);
    int*      dbins  = (int*)alloc(64 * 4);
    int*      dfill  = (int*)alloc(64 * 4);
    int*      perm   = (int*)alloc((size_t)N * 4);
    short*    Whi_t  = (short*)alloc((size_t)WTOT * 2);
    short*    Wlo_t  = (short*)alloc((size_t)WTOT * 2);
    _Float16* XA     = (_Float16*)alloc((size_t)N * FF * 2);
    _Float16* XB     = (_Float16*)alloc((size_t)N * FF * 2);
    _Float16* B1     = (_Float16*)alloc((size_t)N * FF * 2);
    _Float16* B2     = (_Float16*)alloc((size_t)N * FF * 2);

    // bucketed CSR build
    hipMemsetAsync(bcnt, 0, (size_t)NBK * 4, stream);
    hipMemsetAsync(bfill, 0, (size_t)NBK * 4, stream);
    hipMemsetAsync(dbins, 0, 64 * 4, stream);
    hipMemsetAsync(dfill, 0, 64 * 4, stream);
    bhist_kernel<<<EB, 256, 0, stream>>>(dst, bcnt);
    wprep_kernel<<<(WTOT + 255) / 256, 256, 0, stream>>>(W0, Wh, Wl, Whi_t, Wlo_t);
    scan_p1_kernel<<<NB2, 256, 0, stream>>>(bcnt, bsum, NBK);
    scan_p2_kernel<<<1, 1024, 0, stream>>>(bsum, NB2);
    scan_p3_kernel<<<NB2, 256, 0, stream>>>(bcnt, bsum, bptr, NBK);
    bscatter_kernel<<<EB, 256, 0, stream>>>(src, dst, bptr, bfill, ebuf);
    csr_build_kernel<<<NBK, 256, 0, stream>>>(ebuf, bptr, rowptr, colsrc, dinv, dinv2, sdeg);
    // degree-sorted permutation
    dsort_p1_kernel<<<(N + 255) / 256, 256, 0, stream>>>(rowptr, dbins, N);
    dsort_p2_kernel<<<1, 64, 0, stream>>>(dbins);
    dsort_p3_kernel<<<(N + 255) / 256, 256, 0, stream>>>(rowptr, dbins, dfill, perm, N);
    fcvt_kernel<<<(N * FF / 4 + 255) / 256, 256, 0, stream>>>(features, dinv, XA, N * FF / 4);

    const _Float16* cur = XA;
    _Float16* nxt = XB;
    int spmm_grid = (N + 15) / 16;
    int gemm_grid = (N + 127) / 128;

    for (int layer = 0; layer < 7; ++layer) {
        const float* b;
        bool last = (layer == 6);
        if (layer == 0)      { b = b0; }
        else if (layer < 6)  { b = bh + (layer - 1) * 128; }
        else                 { b = bl; }
        const short* whl = Whi_t + (size_t)layer * 128 * 384;
        const short* wll = Wlo_t + (size_t)layer * 128 * 384;

        spmm_h_kernel<<<spmm_grid, 256, 0, stream>>>(B1, cur, cur, dinv2, rowptr, colsrc, perm, -1.f, 0.f, N);
        spmm_h_kernel<<<spmm_grid, 256, 0, stream>>>(B2, B1, cur, dinv2, rowptr, colsrc, perm, -2.f, -1.f, N);

        if (!last)
            gemm_mfma5_kernel<128, 8, true><<<gemm_grid, 256, 0, stream>>>(
                (void*)nxt, cur, B1, B2, whl, wll, b, sdeg, dinv, N);
        else
            gemm_mfma5_kernel<40, 3, false><<<gemm_grid, 256, 0, stream>>>(
                (void*)out, cur, B1, B2, whl, wll, b, sdeg, dinv, N);

        if (layer < 6) {
            const _Float16* newcur = nxt;
            nxt = (_Float16*)((nxt == XB) ? XA : XB);
            cur = newcur;
        }
    }
}

// Round 10
// 2625.925 us; speedup vs baseline: 1.0012x; 1.0012x over previous
//
#include <hip/hip_runtime.h>
#include <hip/hip_bf16.h>

// ChebNet: N=100000, E=1600000, IN=HID=128, OUT=40, K=3, 5 hidden layers.
//  v8: - WINDOW-LOCAL degree sort (64-node windows, wave-shuffle bitonic):
//        waves get degree-adjacent nodes (less divergence waste) while keeping
//        all reads/writes inside the window -> locality of v6 preserved.
//        (v7's global degree sort destroyed locality and its 64-counter global
//        atomics alone cost 262 us -> reverted.)
//      - activations fp16 in SCALED space Z = dinv .* Y (spmm = pure gather-sum).
//      - bucketed CSR build (dst>>6): LDS hist + packed scatter + counting sort.
//      - GEMM: bf16x3 split MFMA, W precomputed [ncol][k] hi/lo, LDS slab copy.

#define NN 100000
#define EE 1600000
#define FF 128
#define NBK 1563           // (NN+63)>>6
#define EPB 4096           // edges per block in bucket passes
#define CAP 3072           // per-bucket staging capacity

typedef __attribute__((ext_vector_type(8))) short short8_t;
typedef __attribute__((ext_vector_type(8))) _Float16 half8_t;
typedef __attribute__((ext_vector_type(4))) _Float16 half4_t;
typedef __attribute__((ext_vector_type(4))) float floatx4;
typedef __attribute__((ext_vector_type(4))) float accfrag;

// ---------------- bucketed CSR build ----------------

__global__ __launch_bounds__(256) void bhist_kernel(const int* __restrict__ dst,
                                                    int* __restrict__ bcnt) {
    __shared__ int lh[NBK];
    int tid = threadIdx.x;
    for (int j = tid; j < NBK; j += 256) lh[j] = 0;
    __syncthreads();
    int e0 = blockIdx.x * EPB;
#pragma unroll
    for (int k = 0; k < EPB / 256; ++k) {
        int i = e0 + k * 256 + tid;
        if (i < EE) atomicAdd(&lh[dst[i] >> 6], 1);
    }
    __syncthreads();
    for (int j = tid; j < NBK; j += 256)
        if (lh[j] > 0) atomicAdd(&bcnt[j], lh[j]);
}

__global__ __launch_bounds__(256) void scan_p1_kernel(const int* __restrict__ cnt,
                                                      int* __restrict__ bsum, int n) {
    __shared__ int red[8];
    int i = blockIdx.x * 256 + threadIdx.x;
    int v = (i < n) ? cnt[i] : 0;
    for (int off = 32; off > 0; off >>= 1) v += __shfl_down(v, off, 64);
    int wv = threadIdx.x >> 6;
    if ((threadIdx.x & 63) == 0) red[wv] = v;
    __syncthreads();
    if (threadIdx.x == 0) bsum[blockIdx.x] = red[0] + red[1] + red[2] + red[3];
}

__global__ __launch_bounds__(1024) void scan_p2_kernel(int* __restrict__ bsum, int nb) {
    __shared__ int s[1024];
    int tid = threadIdx.x;
    int v = (tid < nb) ? bsum[tid] : 0;
    s[tid] = v;
    __syncthreads();
    for (int off = 1; off < 1024; off <<= 1) {
        int u = (tid >= off) ? s[tid - off] : 0;
        __syncthreads();
        s[tid] += u;
        __syncthreads();
    }
    if (tid < nb) bsum[tid] = s[tid] - v;
}

__global__ __launch_bounds__(256) void scan_p3_kernel(const int* __restrict__ cnt,
                                                      const int* __restrict__ bsum,
                                                      int* __restrict__ out_ptr, int n) {
    __shared__ int s[256];
    int tid = threadIdx.x;
    int i = blockIdx.x * 256 + tid;
    int v = (i < n) ? cnt[i] : 0;
    s[tid] = v;
    __syncthreads();
    for (int off = 1; off < 256; off <<= 1) {
        int u = (tid >= off) ? s[tid - off] : 0;
        __syncthreads();
        s[tid] += u;
        __syncthreads();
    }
    if (i < n) {
        int excl = bsum[blockIdx.x] + s[tid] - v;
        out_ptr[i] = excl;
        if (i == n - 1) out_ptr[n] = excl + v;
    }
}

__global__ __launch_bounds__(256) void bscatter_kernel(
    const int* __restrict__ src, const int* __restrict__ dst,
    const int* __restrict__ bptr, int* __restrict__ bfill, int* __restrict__ ebuf) {
    __shared__ int lh[NBK];
    __shared__ int lbase[NBK];
    int tid = threadIdx.x;
    for (int j = tid; j < NBK; j += 256) lh[j] = 0;
    __syncthreads();
    int e0 = blockIdx.x * EPB;
#pragma unroll
    for (int k = 0; k < EPB / 256; ++k) {
        int i = e0 + k * 256 + tid;
        if (i < EE) atomicAdd(&lh[dst[i] >> 6], 1);
    }
    __syncthreads();
    for (int j = tid; j < NBK; j += 256)
        if (lh[j] > 0) lbase[j] = atomicAdd(&bfill[j], lh[j]);
    __syncthreads();
    for (int j = tid; j < NBK; j += 256) lh[j] = 0;
    __syncthreads();
#pragma unroll
    for (int k = 0; k < EPB / 256; ++k) {
        int i = e0 + k * 256 + tid;
        if (i < EE) {
            int d = dst[i];
            int b = d >> 6;
            int off = atomicAdd(&lh[b], 1);
            ebuf[bptr[b] + lbase[b] + off] = (src[i] << 6) | (d & 63);
        }
    }
}

__global__ __launch_bounds__(256) void csr_build_kernel(
    const int* __restrict__ ebuf, const int* __restrict__ bptr,
    int* __restrict__ rowptr, int* __restrict__ colsrc,
    float* __restrict__ dinv, float* __restrict__ dinv2, float* __restrict__ sdeg) {
    __shared__ int pk[CAP];
    __shared__ int ob[CAP];
    __shared__ int cnt[64];
    __shared__ int sexcl[64];
    __shared__ int fill[64];

    int tid = threadIdx.x;
    int b = blockIdx.x;
    int start = bptr[b];
    int cb = bptr[b + 1] - start;
    if (cb > CAP) cb = CAP;

    if (tid < 64) { cnt[tid] = 0; fill[tid] = 0; }
    __syncthreads();

    for (int i = tid; i < cb; i += 256) {
        int v = ebuf[start + i];
        pk[i] = v;
        atomicAdd(&cnt[v & 63], 1);
    }
    __syncthreads();

    if (tid < 64) {
        int v = cnt[tid];
        int inc = v;
        for (int off = 1; off < 64; off <<= 1) {
            int u = __shfl_up(inc, off, 64);
            if (tid >= off) inc += u;
        }
        int excl = inc - v;
        sexcl[tid] = excl;
        int gnode = b * 64 + tid;
        if (gnode < NN) {
            rowptr[gnode] = start + excl;
            int d = v < 1 ? 1 : v;
            float fd = (float)d;
            dinv[gnode]  = 1.0f / sqrtf(fd);
            dinv2[gnode] = 1.0f / fd;
            sdeg[gnode]  = sqrtf(fd);
        }
    }
    if (b == 0 && tid == 0) rowptr[NN] = EE;
    __syncthreads();

    for (int i = tid; i < cb; i += 256) {
        int v = pk[i];
        int d = v & 63;
        int off = atomicAdd(&fill[d], 1);
        ob[sexcl[d] + off] = v >> 6;
    }
    __syncthreads();

    for (int i = tid; i < cb; i += 256) colsrc[start + i] = ob[i];
}

// ---------------- window-local degree sort (64-node windows, wave bitonic) ----------------
// perm[w*64 + rank] = node, nodes of window w sorted by degree. No global atomics.

__global__ __launch_bounds__(256) void wsort_kernel(const int* __restrict__ rowptr,
                                                    int* __restrict__ perm, int n) {
    int lane = threadIdx.x & 63;
    int w = blockIdx.x * 4 + (threadIdx.x >> 6);
    int base = w * 64;
    if (base >= n) return;
    int node = base + lane;
    int deg = (node < n) ? (rowptr[node + 1] - rowptr[node]) : (1 << 20);
    if (deg > 16383) deg = 16383;
    unsigned key = ((unsigned)deg << 6) | (unsigned)lane;   // unique keys
    int val = node;
#pragma unroll
    for (int k = 2; k <= 64; k <<= 1) {
#pragma unroll
        for (int j = k >> 1; j > 0; j >>= 1) {
            unsigned okey = (unsigned)__shfl_xor((int)key, j, 64);
            int oval = __shfl_xor(val, j, 64);
            bool lower = (lane & j) == 0;
            bool up = (lane & k) == 0;
            bool keepmin = (lower == up);
            if ((key > okey) == keepmin) { key = okey; val = oval; }
        }
    }
    if (base + lane < n) perm[base + lane] = val;
}

// ---------------- fp32 -> bf16 hi/lo split (round both) ----------------

__device__ inline void f2bf_hilo(float x, short* hi, short* lo) {
    union { float f; unsigned u; } a; a.f = x;
    unsigned uh = a.u + 0x7FFFu + ((a.u >> 16) & 1u);
    unsigned short h = (unsigned short)(uh >> 16);
    union { unsigned u; float f; } hf; hf.u = ((unsigned)h) << 16;
    float r = x - hf.f;
    union { float f; unsigned u; } b; b.f = r;
    unsigned ul = b.u + 0x7FFFu + ((b.u >> 16) & 1u);
    *hi = (short)h; *lo = (short)(ul >> 16);
}

__device__ inline void split8a(const float* f, short8_t* hi, short8_t* lo) {
    short h[8], l[8];
#pragma unroll
    for (int i = 0; i < 8; ++i) {
        union { float f; unsigned u; } x; x.f = f[i];
        unsigned hu = x.u & 0xFFFF0000u;
        h[i] = (short)(hu >> 16);
        union { unsigned u; float f; } hf; hf.u = hu;
        float r = f[i] - hf.f;
        union { float f; unsigned u; } rr; rr.f = r;
        unsigned ul = rr.u + 0x7FFFu + ((rr.u >> 16) & 1u);
        l[i] = (short)(ul >> 16);
    }
    *hi = (short8_t){ h[0], h[1], h[2], h[3], h[4], h[5], h[6], h[7] };
    *lo = (short8_t){ l[0], l[1], l[2], l[3], l[4], l[5], l[6], l[7] };
}

// ---------------- W precompute: [layer][ncol(128)][k(384)] hi/lo bf16 ----------------

__global__ __launch_bounds__(256) void wprep_kernel(
    const float* __restrict__ W0, const float* __restrict__ Wh, const float* __restrict__ Wl,
    short* __restrict__ Whi_t, short* __restrict__ Wlo_t)
{
    int idx = blockIdx.x * 256 + threadIdx.x;
    const int PER = 128 * 384;
    if (idx >= 7 * PER) return;
    int layer = idx / PER;
    int rem = idx - layer * PER;
    int ncol = rem / 384;
    int k = rem - ncol * 384;
    const float* W; int outc;
    if (layer == 0)      { W = W0; outc = 128; }
    else if (layer < 6)  { W = Wh + (size_t)(layer - 1) * 384 * 128; outc = 128; }
    else                 { W = Wl; outc = 40; }
    float v = (ncol < outc) ? W[(size_t)k * outc + ncol] : 0.f;
    short h, l;
    f2bf_hilo(v, &h, &l);
    Whi_t[idx] = h;
    Wlo_t[idx] = l;
}

// ---------------- feature convert: Z0 = dinv .* X, fp16 ----------------

__global__ __launch_bounds__(256) void fcvt_kernel(const float* __restrict__ in,
                                                   const float* __restrict__ dinv,
                                                   _Float16* __restrict__ out, int total4) {
    int i = blockIdx.x * 256 + threadIdx.x;
    if (i >= total4) return;
    int node = i >> 5;
    float dv = dinv[node];
    floatx4 v = *(const floatx4*)&in[i * 4];
    half4_t r = { (_Float16)(dv * v.x), (_Float16)(dv * v.y),
                  (_Float16)(dv * v.z), (_Float16)(dv * v.w) };
    *(half4_t*)&out[i * 4] = r;
}

// ---------------- SpMM (Z-space, pure gather-sum, window-sorted) ----------------
// Zout[d] = alpha*dinv2[d]*sum_e Zin[src] + beta*Zo[d],  d = perm[g] (same 64-window)

__global__ __launch_bounds__(256, 8) void spmm_h_kernel(
    _Float16* __restrict__ out, const _Float16* __restrict__ Xin,
    const _Float16* __restrict__ Xo, const float* __restrict__ dinv2,
    const int* __restrict__ rp, const int* __restrict__ cs,
    const int* __restrict__ perm, float alpha, float beta, int n)
{
    int slot = threadIdx.x >> 4;
    int lane = threadIdx.x & 15;
    int g = blockIdx.x * 16 + slot;
    if (g >= n) return;
    int node = perm[g];
    const half8_t* X8 = (const half8_t*)Xin;
    float acc[8] = { 0.f, 0.f, 0.f, 0.f, 0.f, 0.f, 0.f, 0.f };
    int s = rp[node], e = rp[node + 1];
    int i = s;
    for (; i + 8 <= e; i += 8) {
        int idx[8];
#pragma unroll
        for (int u = 0; u < 8; ++u) idx[u] = cs[i + u];
        half8_t x[8];
#pragma unroll
        for (int u = 0; u < 8; ++u) x[u] = X8[(size_t)idx[u] * 16 + lane];
#pragma unroll
        for (int u = 0; u < 8; ++u)
#pragma unroll
            for (int j = 0; j < 8; ++j) acc[j] += (float)x[u][j];
    }
    for (; i < e; ++i) {
        int sidx = cs[i];
        half8_t x = X8[(size_t)sidx * 16 + lane];
#pragma unroll
        for (int j = 0; j < 8; ++j) acc[j] += (float)x[j];
    }
    float sc = alpha * dinv2[node];
    half8_t r;
    if (beta != 0.f) {
        half8_t o = ((const half8_t*)Xo)[(size_t)node * 16 + lane];
#pragma unroll
        for (int j = 0; j < 8; ++j) r[j] = (_Float16)(sc * acc[j] + beta * (float)o[j]);
    } else {
#pragma unroll
        for (int j = 0; j < 8; ++j) r[j] = (_Float16)(sc * acc[j]);
    }
    ((half8_t*)out)[(size_t)node * 16 + lane] = r;
}

// ---------------- GEMM: LDS W-slab bf16x3 MFMA, Z-space A ----------------

template <int OUTC, int NT, bool HOUT>
__global__ __launch_bounds__(256, 2) void gemm_mfma5_kernel(
    void* __restrict__ outp, const _Float16* __restrict__ X0,
    const _Float16* __restrict__ X1, const _Float16* __restrict__ X2,
    const short* __restrict__ Whi_t, const short* __restrict__ Wlo_t,
    const float* __restrict__ bias, const float* __restrict__ sdeg,
    const float* __restrict__ dinv, int n)
{
    __shared__ short Ws[2][NT * 16][136];

    int tid = threadIdx.x;
    int lane = tid & 63;
    int wave = tid >> 6;
    int m15 = lane & 15;
    int quad = lane >> 4;
    int row0 = blockIdx.x * 128 + wave * 32;

    accfrag acc[2][NT];
#pragma unroll
    for (int mi = 0; mi < 2; ++mi)
#pragma unroll
        for (int nj = 0; nj < NT; ++nj) acc[mi][nj] = (accfrag){0.f, 0.f, 0.f, 0.f};

    int r0 = row0 + m15;
    int r1 = r0 + 16;
    float s0 = (r0 < n) ? sdeg[r0] : 0.f;
    float s1 = (r1 < n) ? sdeg[r1] : 0.f;
    size_t ro0 = (size_t)((r0 < n) ? r0 : 0) * 16;
    size_t ro1 = (size_t)((r1 < n) ? r1 : 0) * 16;

    const _Float16* srcs[3] = { X0, X1, X2 };

    for (int sb = 0; sb < 3; ++sb) {
        {
            const int VEC = NT * 512;
#pragma unroll
            for (int v0 = 0; v0 < VEC; v0 += 256) {
                int v = v0 + tid;
                int a = (v >= NT * 256) ? 1 : 0;
                int rem = v - a * (NT * 256);
                int row = rem >> 4;
                int c8 = (rem & 15) * 8;
                const short* g = (a ? Wlo_t : Whi_t) + (size_t)row * 384 + sb * 128 + c8;
                *(short8_t*)&Ws[a][row][c8] = *(const short8_t*)g;
            }
        }
        __syncthreads();

        const half8_t* Xp8 = (const half8_t*)srcs[sb];
#pragma unroll
        for (int kk = 0; kk < 4; ++kk) {
            int k0 = kk * 32 + quad * 8;
            half8_t h0 = Xp8[ro0 + kk * 4 + quad];
            half8_t h1 = Xp8[ro1 + kk * 4 + quad];
            float f0[8], f1[8];
#pragma unroll
            for (int j = 0; j < 8; ++j) { f0[j] = s0 * (float)h0[j]; f1[j] = s1 * (float)h1[j]; }
            short8_t a_hi[2], a_lo[2];
            split8a(f0, &a_hi[0], &a_lo[0]);
            split8a(f1, &a_hi[1], &a_lo[1]);

#pragma unroll
            for (int nj = 0; nj < NT; ++nj) {
                short8_t b_hi = *(const short8_t*)&Ws[0][nj * 16 + m15][k0];
                short8_t b_lo = *(const short8_t*)&Ws[1][nj * 16 + m15][k0];
#pragma unroll
                for (int mi = 0; mi < 2; ++mi) {
                    acc[mi][nj] = __builtin_amdgcn_mfma_f32_16x16x32_bf16(a_hi[mi], b_hi, acc[mi][nj], 0, 0, 0);
                    acc[mi][nj] = __builtin_amdgcn_mfma_f32_16x16x32_bf16(a_lo[mi], b_hi, acc[mi][nj], 0, 0, 0);
                    acc[mi][nj] = __builtin_amdgcn_mfma_f32_16x16x32_bf16(a_hi[mi], b_lo, acc[mi][nj], 0, 0, 0);
                }
            }
        }
        __syncthreads();
    }

    float dvs[2][4];
    if (HOUT) {
#pragma unroll
        for (int mi = 0; mi < 2; ++mi)
#pragma unroll
            for (int reg = 0; reg < 4; ++reg) {
                int gr = row0 + mi * 16 + quad * 4 + reg;
                dvs[mi][reg] = (gr < n) ? dinv[gr] : 0.f;
            }
    }
#pragma unroll
    for (int nj = 0; nj < NT; ++nj) {
        int col = nj * 16 + m15;
        float bv = (col < OUTC) ? bias[col] : 0.f;
#pragma unroll
        for (int mi = 0; mi < 2; ++mi) {
#pragma unroll
            for (int reg = 0; reg < 4; ++reg) {
                int gr = row0 + mi * 16 + quad * 4 + reg;
                if (gr < n && col < OUTC) {
                    float v = acc[mi][nj][reg] + bv;
                    v = v > 0.f ? v : 0.f;
                    if (HOUT) ((_Float16*)outp)[(size_t)gr * OUTC + col] = (_Float16)(v * dvs[mi][reg]);
                    else      ((float*)outp)[(size_t)gr * OUTC + col] = v;
                }
            }
        }
    }
}

// ---------------- launch ----------------

extern "C" void kernel_launch(void* const* d_in, const int* in_sizes, int n_in,
                              void* d_out, int out_size, void* d_ws, size_t ws_size,
                              hipStream_t stream) {
    const float* features = (const float*)d_in[0];
    const int*   src      = (const int*)d_in[1];
    const int*   dst      = (const int*)d_in[2];
    const float* W0       = (const float*)d_in[3];
    const float* b0       = (const float*)d_in[4];
    const float* Wh       = (const float*)d_in[5];
    const float* bh       = (const float*)d_in[6];
    const float* Wl       = (const float*)d_in[7];
    const float* bl       = (const float*)d_in[8];
    float* out = (float*)d_out;

    const int N = NN, E = EE;
    const int WTOT = 7 * 128 * 384;
    const int EB = (E + EPB - 1) / EPB;
    const int NB2 = (NBK + 255) / 256;

    char* ws = (char*)d_ws;
    size_t off = 0;
    auto alloc = [&](size_t bytes) -> void* {
        void* p = ws + off;
        off += (bytes + 511) & ~(size_t)511;
        return p;
    };
    int*      bcnt   = (int*)alloc((size_t)NBK * 4);
    int*      bfill  = (int*)alloc((size_t)NBK * 4);
    int*      bptr   = (int*)alloc((size_t)(NBK + 1) * 4);
    int*      bsum   = (int*)alloc((size_t)NB2 * 4);
    int*      rowptr = (int*)alloc((size_t)(N + 1) * 4);
    int*      ebuf   = (int*)alloc((size_t)E * 4);
    int*      colsrc = (int*)alloc((size_t)E * 4);
    float*    dinv   = (float*)alloc((size_t)N * 4);
    float*    dinv2  = (float*)alloc((size_t)N * 4);
    float*    sdeg   = (float*)alloc((size_t)N * 4);
    int*      perm   = (int*)alloc((size_t)N * 4);
    short*    Whi_t  = (short*)alloc((size_t)WTOT * 2);
    short*    Wlo_t  = (short*)alloc((size_t)WTOT * 2);
    _Float16* XA     = (_Float16*)alloc((size_t)N * FF * 2);
    _Float16* XB     = (_Float16*)alloc((size_t)N * FF * 2);
    _Float16* B1     = (_Float16*)alloc((size_t)N * FF * 2);
    _Float16* B2     = (_Float16*)alloc((size_t)N * FF * 2);

    // bucketed CSR build
    hipMemsetAsync(bcnt, 0, (size_t)NBK * 4, stream);
    hipMemsetAsync(bfill, 0, (size_t)NBK * 4, stream);
    bhist_kernel<<<EB, 256, 0, stream>>>(dst, bcnt);
    wprep_kernel<<<(WTOT + 255) / 256, 256, 0, stream>>>(W0, Wh, Wl, Whi_t, Wlo_t);
    scan_p1_kernel<<<NB2, 256, 0, stream>>>(bcnt, bsum, NBK);
    scan_p2_kernel<<<1, 1024, 0, stream>>>(bsum, NB2);
    scan_p3_kernel<<<NB2, 256, 0, stream>>>(bcnt, bsum, bptr, NBK);
    bscatter_kernel<<<EB, 256, 0, stream>>>(src, dst, bptr, bfill, ebuf);
    csr_build_kernel<<<NBK, 256, 0, stream>>>(ebuf, bptr, rowptr, colsrc, dinv, dinv2, sdeg);
    wsort_kernel<<<(N + 255) / 256, 256, 0, stream>>>(rowptr, perm, N);
    fcvt_kernel<<<(N * FF / 4 + 255) / 256, 256, 0, stream>>>(features, dinv, XA, N * FF / 4);

    const _Float16* cur = XA;
    _Float16* nxt = XB;
    int spmm_grid = (N + 15) / 16;
    int gemm_grid = (N + 127) / 128;

    for (int layer = 0; layer < 7; ++layer) {
        const float* b;
        bool last = (layer == 6);
        if (layer == 0)      { b = b0; }
        else if (layer < 6)  { b = bh + (layer - 1) * 128; }
        else                 { b = bl; }
        const short* whl = Whi_t + (size_t)layer * 128 * 384;
        const short* wll = Wlo_t + (size_t)layer * 128 * 384;

        spmm_h_kernel<<<spmm_grid, 256, 0, stream>>>(B1, cur, cur, dinv2, rowptr, colsrc, perm, -1.f, 0.f, N);
        spmm_h_kernel<<<spmm_grid, 256, 0, stream>>>(B2, B1, cur, dinv2, rowptr, colsrc, perm, -2.f, -1.f, N);

        if (!last)
            gemm_mfma5_kernel<128, 8, true><<<gemm_grid, 256, 0, stream>>>(
                (void*)nxt, cur, B1, B2, whl, wll, b, sdeg, dinv, N);
        else
            gemm_mfma5_kernel<40, 3, false><<<gemm_grid, 256, 0, stream>>>(
                (void*)out, cur, B1, B2, whl, wll, b, sdeg, dinv, N);

        if (layer < 6) {
            const _Float16* newcur = nxt;
            nxt = (_Float16*)((nxt == XB) ? XA : XB);
            cur = newcur;
        }
    }
}

// Round 11
// 1427.649 us; speedup vs baseline: 1.8416x; 1.8393x over previous
//
#include <hip/hip_runtime.h>
#include <hip/hip_bf16.h>

// ChebNet: N=100000, E=1600000, IN=HID=128, OUT=40, K=3, 5 hidden layers.
//  v9 = v6 (round-8, 1437us) + GEMM epilogue-scale rework.
//  - activations fp16 in SCALED space Z = dinv .* Y (spmm = pure gather-sum).
//    spmm node order LINEAR (v7/v8 degree-perm destroyed write coalescing:
//    WRITE_SIZE 25->230 MB. Do not permute.)
//  - bucketed CSR build (dst>>6): LDS hist + packed scatter + counting sort.
//  - GEMM: bf16x3 MFMA on Z directly; sdeg row-scale folded into epilogue
//    (for hidden layers dinv*relu(sdeg*acc+b) == relu(acc + dinv*b)).
//    A split = pure truncation (exact for fp16 values), packed with v_perm.

#define NN 100000
#define EE 1600000
#define FF 128
#define NBK 1563           // (NN+63)>>6
#define EPB 4096           // edges per block in bucket passes
#define CAP 3072           // per-bucket staging capacity

typedef __attribute__((ext_vector_type(8))) short short8_t;
typedef __attribute__((ext_vector_type(8))) _Float16 half8_t;
typedef __attribute__((ext_vector_type(4))) _Float16 half4_t;
typedef __attribute__((ext_vector_type(4))) float floatx4;
typedef __attribute__((ext_vector_type(4))) float accfrag;

// ---------------- bucketed CSR build ----------------

__global__ __launch_bounds__(256) void bhist_kernel(const int* __restrict__ dst,
                                                    int* __restrict__ bcnt) {
    __shared__ int lh[NBK];
    int tid = threadIdx.x;
    for (int j = tid; j < NBK; j += 256) lh[j] = 0;
    __syncthreads();
    int e0 = blockIdx.x * EPB;
#pragma unroll
    for (int k = 0; k < EPB / 256; ++k) {
        int i = e0 + k * 256 + tid;
        if (i < EE) atomicAdd(&lh[dst[i] >> 6], 1);
    }
    __syncthreads();
    for (int j = tid; j < NBK; j += 256)
        if (lh[j] > 0) atomicAdd(&bcnt[j], lh[j]);
}

__global__ __launch_bounds__(256) void scan_p1_kernel(const int* __restrict__ cnt,
                                                      int* __restrict__ bsum, int n) {
    __shared__ int red[8];
    int i = blockIdx.x * 256 + threadIdx.x;
    int v = (i < n) ? cnt[i] : 0;
    for (int off = 32; off > 0; off >>= 1) v += __shfl_down(v, off, 64);
    int wv = threadIdx.x >> 6;
    if ((threadIdx.x & 63) == 0) red[wv] = v;
    __syncthreads();
    if (threadIdx.x == 0) bsum[blockIdx.x] = red[0] + red[1] + red[2] + red[3];
}

__global__ __launch_bounds__(1024) void scan_p2_kernel(int* __restrict__ bsum, int nb) {
    __shared__ int s[1024];
    int tid = threadIdx.x;
    int v = (tid < nb) ? bsum[tid] : 0;
    s[tid] = v;
    __syncthreads();
    for (int off = 1; off < 1024; off <<= 1) {
        int u = (tid >= off) ? s[tid - off] : 0;
        __syncthreads();
        s[tid] += u;
        __syncthreads();
    }
    if (tid < nb) bsum[tid] = s[tid] - v;
}

__global__ __launch_bounds__(256) void scan_p3_kernel(const int* __restrict__ cnt,
                                                      const int* __restrict__ bsum,
                                                      int* __restrict__ out_ptr, int n) {
    __shared__ int s[256];
    int tid = threadIdx.x;
    int i = blockIdx.x * 256 + tid;
    int v = (i < n) ? cnt[i] : 0;
    s[tid] = v;
    __syncthreads();
    for (int off = 1; off < 256; off <<= 1) {
        int u = (tid >= off) ? s[tid - off] : 0;
        __syncthreads();
        s[tid] += u;
        __syncthreads();
    }
    if (i < n) {
        int excl = bsum[blockIdx.x] + s[tid] - v;
        out_ptr[i] = excl;
        if (i == n - 1) out_ptr[n] = excl + v;
    }
}

__global__ __launch_bounds__(256) void bscatter_kernel(
    const int* __restrict__ src, const int* __restrict__ dst,
    const int* __restrict__ bptr, int* __restrict__ bfill, int* __restrict__ ebuf) {
    __shared__ int lh[NBK];
    __shared__ int lbase[NBK];
    int tid = threadIdx.x;
    for (int j = tid; j < NBK; j += 256) lh[j] = 0;
    __syncthreads();
    int e0 = blockIdx.x * EPB;
#pragma unroll
    for (int k = 0; k < EPB / 256; ++k) {
        int i = e0 + k * 256 + tid;
        if (i < EE) atomicAdd(&lh[dst[i] >> 6], 1);
    }
    __syncthreads();
    for (int j = tid; j < NBK; j += 256)
        if (lh[j] > 0) lbase[j] = atomicAdd(&bfill[j], lh[j]);
    __syncthreads();
    for (int j = tid; j < NBK; j += 256) lh[j] = 0;
    __syncthreads();
#pragma unroll
    for (int k = 0; k < EPB / 256; ++k) {
        int i = e0 + k * 256 + tid;
        if (i < EE) {
            int d = dst[i];
            int b = d >> 6;
            int off = atomicAdd(&lh[b], 1);
            ebuf[bptr[b] + lbase[b] + off] = (src[i] << 6) | (d & 63);
        }
    }
}

__global__ __launch_bounds__(256) void csr_build_kernel(
    const int* __restrict__ ebuf, const int* __restrict__ bptr,
    int* __restrict__ rowptr, int* __restrict__ colsrc,
    float* __restrict__ dinv, float* __restrict__ dinv2, float* __restrict__ sdeg) {
    __shared__ int pk[CAP];
    __shared__ int ob[CAP];
    __shared__ int cnt[64];
    __shared__ int sexcl[64];
    __shared__ int fill[64];

    int tid = threadIdx.x;
    int b = blockIdx.x;
    int start = bptr[b];
    int cb = bptr[b + 1] - start;
    if (cb > CAP) cb = CAP;

    if (tid < 64) { cnt[tid] = 0; fill[tid] = 0; }
    __syncthreads();

    for (int i = tid; i < cb; i += 256) {
        int v = ebuf[start + i];
        pk[i] = v;
        atomicAdd(&cnt[v & 63], 1);
    }
    __syncthreads();

    if (tid < 64) {
        int v = cnt[tid];
        int inc = v;
        for (int off = 1; off < 64; off <<= 1) {
            int u = __shfl_up(inc, off, 64);
            if (tid >= off) inc += u;
        }
        int excl = inc - v;
        sexcl[tid] = excl;
        int gnode = b * 64 + tid;
        if (gnode < NN) {
            rowptr[gnode] = start + excl;
            int d = v < 1 ? 1 : v;
            float fd = (float)d;
            dinv[gnode]  = 1.0f / sqrtf(fd);
            dinv2[gnode] = 1.0f / fd;
            sdeg[gnode]  = sqrtf(fd);
        }
    }
    if (b == 0 && tid == 0) rowptr[NN] = EE;
    __syncthreads();

    for (int i = tid; i < cb; i += 256) {
        int v = pk[i];
        int d = v & 63;
        int off = atomicAdd(&fill[d], 1);
        ob[sexcl[d] + off] = v >> 6;
    }
    __syncthreads();

    for (int i = tid; i < cb; i += 256) colsrc[start + i] = ob[i];
}

// ---------------- fp32 -> bf16 hi/lo split (round both; wprep only) ----------------

__device__ inline void f2bf_hilo(float x, short* hi, short* lo) {
    union { float f; unsigned u; } a; a.f = x;
    unsigned uh = a.u + 0x7FFFu + ((a.u >> 16) & 1u);
    unsigned short h = (unsigned short)(uh >> 16);
    union { unsigned u; float f; } hf; hf.u = ((unsigned)h) << 16;
    float r = x - hf.f;
    union { float f; unsigned u; } b; b.f = r;
    unsigned ul = b.u + 0x7FFFu + ((b.u >> 16) & 1u);
    *hi = (short)h; *lo = (short)(ul >> 16);
}

// truncation split, packed via v_perm. EXACT for fp16-origin values
// (fp16: 11 mantissa bits = 7 in hi-bf16 + <=4 in exact residual lo-bf16).
__device__ inline void split8t(const float* f, short8_t* hi, short8_t* lo) {
    unsigned hp[4], lp[4];
#pragma unroll
    for (int i = 0; i < 4; ++i) {
        union { float f; unsigned u; } a, b;
        a.f = f[2 * i]; b.f = f[2 * i + 1];
        union { unsigned u; float f; } fa, fb;
        fa.u = a.u & 0xFFFF0000u;
        fb.u = b.u & 0xFFFF0000u;
        union { float f; unsigned u; } ra, rb;
        ra.f = a.f - fa.f;
        rb.f = b.f - fb.f;
        hp[i] = __builtin_amdgcn_perm(b.u, a.u, 0x07060302u);
        lp[i] = __builtin_amdgcn_perm(rb.u, ra.u, 0x07060302u);
    }
    union { unsigned u[4]; short8_t s; } H, L;
    H.u[0] = hp[0]; H.u[1] = hp[1]; H.u[2] = hp[2]; H.u[3] = hp[3];
    L.u[0] = lp[0]; L.u[1] = lp[1]; L.u[2] = lp[2]; L.u[3] = lp[3];
    *hi = H.s; *lo = L.s;
}

// ---------------- W precompute: [layer][ncol(128)][k(384)] hi/lo bf16 ----------------

__global__ __launch_bounds__(256) void wprep_kernel(
    const float* __restrict__ W0, const float* __restrict__ Wh, const float* __restrict__ Wl,
    short* __restrict__ Whi_t, short* __restrict__ Wlo_t)
{
    int idx = blockIdx.x * 256 + threadIdx.x;
    const int PER = 128 * 384;
    if (idx >= 7 * PER) return;
    int layer = idx / PER;
    int rem = idx - layer * PER;
    int ncol = rem / 384;
    int k = rem - ncol * 384;
    const float* W; int outc;
    if (layer == 0)      { W = W0; outc = 128; }
    else if (layer < 6)  { W = Wh + (size_t)(layer - 1) * 384 * 128; outc = 128; }
    else                 { W = Wl; outc = 40; }
    float v = (ncol < outc) ? W[(size_t)k * outc + ncol] : 0.f;
    short h, l;
    f2bf_hilo(v, &h, &l);
    Whi_t[idx] = h;
    Wlo_t[idx] = l;
}

// ---------------- feature convert: Z0 = dinv .* X, fp16 ----------------

__global__ __launch_bounds__(256) void fcvt_kernel(const float* __restrict__ in,
                                                   const float* __restrict__ dinv,
                                                   _Float16* __restrict__ out, int total4) {
    int i = blockIdx.x * 256 + threadIdx.x;
    if (i >= total4) return;
    int node = i >> 5;
    float dv = dinv[node];
    floatx4 v = *(const floatx4*)&in[i * 4];
    half4_t r = { (_Float16)(dv * v.x), (_Float16)(dv * v.y),
                  (_Float16)(dv * v.z), (_Float16)(dv * v.w) };
    *(half4_t*)&out[i * 4] = r;
}

// ---------------- SpMM (Z-space, pure gather-sum, LINEAR node order) ----------------
// Zout[d] = alpha*dinv2[d]*sum_e Zin[src] + beta*Zo[d]

__global__ __launch_bounds__(256) void spmm_h_kernel(
    _Float16* __restrict__ out, const _Float16* __restrict__ Xin,
    const _Float16* __restrict__ Xo, const float* __restrict__ dinv2,
    const int* __restrict__ rp, const int* __restrict__ cs,
    float alpha, float beta, int n)
{
    int slot = threadIdx.x >> 4;
    int lane = threadIdx.x & 15;
    int node = blockIdx.x * 16 + slot;
    if (node >= n) return;
    const half8_t* X8 = (const half8_t*)Xin;
    float acc[8] = { 0.f, 0.f, 0.f, 0.f, 0.f, 0.f, 0.f, 0.f };
    int s = rp[node], e = rp[node + 1];
    int i = s;
    for (; i + 8 <= e; i += 8) {
        int idx[8];
#pragma unroll
        for (int u = 0; u < 8; ++u) idx[u] = cs[i + u];
        half8_t x[8];
#pragma unroll
        for (int u = 0; u < 8; ++u) x[u] = X8[(size_t)idx[u] * 16 + lane];
#pragma unroll
        for (int u = 0; u < 8; ++u)
#pragma unroll
            for (int j = 0; j < 8; ++j) acc[j] += (float)x[u][j];
    }
    for (; i < e; ++i) {
        int sidx = cs[i];
        half8_t x = X8[(size_t)sidx * 16 + lane];
#pragma unroll
        for (int j = 0; j < 8; ++j) acc[j] += (float)x[j];
    }
    float sc = alpha * dinv2[node];
    half8_t r;
    if (beta != 0.f) {
        half8_t o = ((const half8_t*)Xo)[(size_t)node * 16 + lane];
#pragma unroll
        for (int j = 0; j < 8; ++j) r[j] = (_Float16)(sc * acc[j] + beta * (float)o[j]);
    } else {
#pragma unroll
        for (int j = 0; j < 8; ++j) r[j] = (_Float16)(sc * acc[j]);
    }
    ((half8_t*)out)[(size_t)node * 16 + lane] = r;
}

// ---------------- GEMM: LDS W-slab bf16x3 MFMA on Z; row scale in epilogue ----------------
// acc = Z·W (A split exact). Hidden: store relu(acc + dinv*b) fp16 (Z-space directly,
// since dinv*relu(sdeg*acc+b) == relu(acc + dinv*b)). Last: store relu(sdeg*acc + b) fp32.

template <int OUTC, int NT, bool HOUT>
__global__ __launch_bounds__(256, 2) void gemm_mfma6_kernel(
    void* __restrict__ outp, const _Float16* __restrict__ X0,
    const _Float16* __restrict__ X1, const _Float16* __restrict__ X2,
    const short* __restrict__ Whi_t, const short* __restrict__ Wlo_t,
    const float* __restrict__ bias, const float* __restrict__ sdeg,
    const float* __restrict__ dinv, int n)
{
    __shared__ short Ws[2][NT * 16][136];

    int tid = threadIdx.x;
    int lane = tid & 63;
    int wave = tid >> 6;
    int m15 = lane & 15;
    int quad = lane >> 4;
    int row0 = blockIdx.x * 128 + wave * 32;

    accfrag acc[2][NT];
#pragma unroll
    for (int mi = 0; mi < 2; ++mi)
#pragma unroll
        for (int nj = 0; nj < NT; ++nj) acc[mi][nj] = (accfrag){0.f, 0.f, 0.f, 0.f};

    int r0 = row0 + m15;
    int r1 = r0 + 16;
    size_t ro0 = (size_t)((r0 < n) ? r0 : 0) * 16;   // half8 units; OOB rows read
    size_t ro1 = (size_t)((r1 < n) ? r1 : 0) * 16;   // row 0, results never stored

    const _Float16* srcs[3] = { X0, X1, X2 };

    for (int sb = 0; sb < 3; ++sb) {
        // stage W slab: NT*16 rows x 128 shorts, hi then lo (contiguous copy)
        {
            const int VEC = NT * 512;
#pragma unroll
            for (int v0 = 0; v0 < VEC; v0 += 256) {
                int v = v0 + tid;
                int a = (v >= NT * 256) ? 1 : 0;
                int rem = v - a * (NT * 256);
                int row = rem >> 4;
                int c8 = (rem & 15) * 8;
                const short* g = (a ? Wlo_t : Whi_t) + (size_t)row * 384 + sb * 128 + c8;
                *(short8_t*)&Ws[a][row][c8] = *(const short8_t*)g;
            }
        }
        __syncthreads();

        const half8_t* Xp8 = (const half8_t*)srcs[sb];
#pragma unroll
        for (int kk = 0; kk < 4; ++kk) {
            int k0 = kk * 32 + quad * 8;
            half8_t h0 = Xp8[ro0 + kk * 4 + quad];
            half8_t h1 = Xp8[ro1 + kk * 4 + quad];
            float f0[8], f1[8];
#pragma unroll
            for (int j = 0; j < 8; ++j) { f0[j] = (float)h0[j]; f1[j] = (float)h1[j]; }
            short8_t a_hi[2], a_lo[2];
            split8t(f0, &a_hi[0], &a_lo[0]);
            split8t(f1, &a_hi[1], &a_lo[1]);

#pragma unroll
            for (int nj = 0; nj < NT; ++nj) {
                short8_t b_hi = *(const short8_t*)&Ws[0][nj * 16 + m15][k0];
                short8_t b_lo = *(const short8_t*)&Ws[1][nj * 16 + m15][k0];
#pragma unroll
                for (int mi = 0; mi < 2; ++mi) {
                    acc[mi][nj] = __builtin_amdgcn_mfma_f32_16x16x32_bf16(a_hi[mi], b_hi, acc[mi][nj], 0, 0, 0);
                    acc[mi][nj] = __builtin_amdgcn_mfma_f32_16x16x32_bf16(a_lo[mi], b_hi, acc[mi][nj], 0, 0, 0);
                    acc[mi][nj] = __builtin_amdgcn_mfma_f32_16x16x32_bf16(a_hi[mi], b_lo, acc[mi][nj], 0, 0, 0);
                }
            }
        }
        __syncthreads();
    }

    // epilogue. C/D: col=lane&15, row=quad*4+reg.
    float rs[2][4];
#pragma unroll
    for (int mi = 0; mi < 2; ++mi)
#pragma unroll
        for (int reg = 0; reg < 4; ++reg) {
            int gr = row0 + mi * 16 + quad * 4 + reg;
            int cg = (gr < n) ? gr : 0;
            rs[mi][reg] = HOUT ? dinv[cg] : sdeg[cg];
        }
#pragma unroll
    for (int nj = 0; nj < NT; ++nj) {
        int col = nj * 16 + m15;
        float bv = (col < OUTC) ? bias[col] : 0.f;
#pragma unroll
        for (int mi = 0; mi < 2; ++mi) {
#pragma unroll
            for (int reg = 0; reg < 4; ++reg) {
                int gr = row0 + mi * 16 + quad * 4 + reg;
                if (gr < n && col < OUTC) {
                    if (HOUT) {
                        float v = acc[mi][nj][reg] + rs[mi][reg] * bv;
                        v = v > 0.f ? v : 0.f;
                        ((_Float16*)outp)[(size_t)gr * OUTC + col] = (_Float16)v;
                    } else {
                        float v = rs[mi][reg] * acc[mi][nj][reg] + bv;
                        v = v > 0.f ? v : 0.f;
                        ((float*)outp)[(size_t)gr * OUTC + col] = v;
                    }
                }
            }
        }
    }
}

// ---------------- launch ----------------

extern "C" void kernel_launch(void* const* d_in, const int* in_sizes, int n_in,
                              void* d_out, int out_size, void* d_ws, size_t ws_size,
                              hipStream_t stream) {
    const float* features = (const float*)d_in[0];
    const int*   src      = (const int*)d_in[1];
    const int*   dst      = (const int*)d_in[2];
    const float* W0       = (const float*)d_in[3];
    const float* b0       = (const float*)d_in[4];
    const float* Wh       = (const float*)d_in[5];
    const float* bh       = (const float*)d_in[6];
    const float* Wl       = (const float*)d_in[7];
    const float* bl       = (const float*)d_in[8];
    float* out = (float*)d_out;

    const int N = NN, E = EE;
    const int WTOT = 7 * 128 * 384;
    const int EB = (E + EPB - 1) / EPB;
    const int NB2 = (NBK + 255) / 256;

    char* ws = (char*)d_ws;
    size_t off = 0;
    auto alloc = [&](size_t bytes) -> void* {
        void* p = ws + off;
        off += (bytes + 511) & ~(size_t)511;
        return p;
    };
    int*      bcnt   = (int*)alloc((size_t)NBK * 4);
    int*      bfill  = (int*)alloc((size_t)NBK * 4);
    int*      bptr   = (int*)alloc((size_t)(NBK + 1) * 4);
    int*      bsum   = (int*)alloc((size_t)NB2 * 4);
    int*      rowptr = (int*)alloc((size_t)(N + 1) * 4);
    int*      ebuf   = (int*)alloc((size_t)E * 4);
    int*      colsrc = (int*)alloc((size_t)E * 4);
    float*    dinv   = (float*)alloc((size_t)N * 4);
    float*    dinv2  = (float*)alloc((size_t)N * 4);
    float*    sdeg   = (float*)alloc((size_t)N * 4);
    short*    Whi_t  = (short*)alloc((size_t)WTOT * 2);
    short*    Wlo_t  = (short*)alloc((size_t)WTOT * 2);
    _Float16* XA     = (_Float16*)alloc((size_t)N * FF * 2);
    _Float16* XB     = (_Float16*)alloc((size_t)N * FF * 2);
    _Float16* B1     = (_Float16*)alloc((size_t)N * FF * 2);
    _Float16* B2     = (_Float16*)alloc((size_t)N * FF * 2);

    // bucketed CSR build
    hipMemsetAsync(bcnt, 0, (size_t)NBK * 4, stream);
    hipMemsetAsync(bfill, 0, (size_t)NBK * 4, stream);
    bhist_kernel<<<EB, 256, 0, stream>>>(dst, bcnt);
    wprep_kernel<<<(WTOT + 255) / 256, 256, 0, stream>>>(W0, Wh, Wl, Whi_t, Wlo_t);
    scan_p1_kernel<<<NB2, 256, 0, stream>>>(bcnt, bsum, NBK);
    scan_p2_kernel<<<1, 1024, 0, stream>>>(bsum, NB2);
    scan_p3_kernel<<<NB2, 256, 0, stream>>>(bcnt, bsum, bptr, NBK);
    bscatter_kernel<<<EB, 256, 0, stream>>>(src, dst, bptr, bfill, ebuf);
    csr_build_kernel<<<NBK, 256, 0, stream>>>(ebuf, bptr, rowptr, colsrc, dinv, dinv2, sdeg);
    fcvt_kernel<<<(N * FF / 4 + 255) / 256, 256, 0, stream>>>(features, dinv, XA, N * FF / 4);

    const _Float16* cur = XA;
    _Float16* nxt = XB;
    int spmm_grid = (N + 15) / 16;
    int gemm_grid = (N + 127) / 128;

    for (int layer = 0; layer < 7; ++layer) {
        const float* b;
        bool last = (layer == 6);
        if (layer == 0)      { b = b0; }
        else if (layer < 6)  { b = bh + (layer - 1) * 128; }
        else                 { b = bl; }
        const short* whl = Whi_t + (size_t)layer * 128 * 384;
        const short* wll = Wlo_t + (size_t)layer * 128 * 384;

        spmm_h_kernel<<<spmm_grid, 256, 0, stream>>>(B1, cur, cur, dinv2, rowptr, colsrc, -1.f, 0.f, N);
        spmm_h_kernel<<<spmm_grid, 256, 0, stream>>>(B2, B1, cur, dinv2, rowptr, colsrc, -2.f, -1.f, N);

        if (!last)
            gemm_mfma6_kernel<128, 8, true><<<gemm_grid, 256, 0, stream>>>(
                (void*)nxt, cur, B1, B2, whl, wll, b, sdeg, dinv, N);
        else
            gemm_mfma6_kernel<40, 3, false><<<gemm_grid, 256, 0, stream>>>(
                (void*)out, cur, B1, B2, whl, wll, b, sdeg, dinv, N);

        if (layer < 6) {
            const _Float16* newcur = nxt;
            nxt = (_Float16*)((nxt == XB) ? XA : XB);
            cur = newcur;
        }
    }
}

// Round 12
// 1296.567 us; speedup vs baseline: 2.0278x; 1.1011x over previous
//
#include <hip/hip_runtime.h>
#include <hip/hip_bf16.h>

// ChebNet: N=100000, E=1600000, IN=HID=128, OUT=40, K=3, 5 hidden layers.
//  v10 = v9 + pure-fp16 MFMA GEMM.
//  - activations fp16 in SCALED space Z = dinv .* Y (spmm = pure gather-sum).
//    spmm node order LINEAR (degree-perm destroyed write coalescing; don't).
//  - bucketed CSR build (dst>>6): LDS hist + packed scatter + counting sort.
//  - GEMM: W converted to fp16 [ncol][k] once; per-sb slab in LDS (34.8 KB ->
//    4 blocks/CU); A = direct half8 loads (no conversion);
//    1x mfma_f32_16x16x32_f16 per tile pair (was 3x bf16 + 40 VALU split).
//    W-quant adds ~2.4e-4 rel/layer: absmax budget ~2.5-3.5e-3 < 5.98e-3.

#define NN 100000
#define EE 1600000
#define FF 128
#define NBK 1563           // (NN+63)>>6
#define EPB 4096           // edges per block in bucket passes
#define CAP 3072           // per-bucket staging capacity

typedef __attribute__((ext_vector_type(8))) short short8_t;
typedef __attribute__((ext_vector_type(8))) _Float16 half8_t;
typedef __attribute__((ext_vector_type(4))) _Float16 half4_t;
typedef __attribute__((ext_vector_type(4))) float floatx4;
typedef __attribute__((ext_vector_type(4))) float accfrag;

// ---------------- bucketed CSR build ----------------

__global__ __launch_bounds__(256) void bhist_kernel(const int* __restrict__ dst,
                                                    int* __restrict__ bcnt) {
    __shared__ int lh[NBK];
    int tid = threadIdx.x;
    for (int j = tid; j < NBK; j += 256) lh[j] = 0;
    __syncthreads();
    int e0 = blockIdx.x * EPB;
#pragma unroll
    for (int k = 0; k < EPB / 256; ++k) {
        int i = e0 + k * 256 + tid;
        if (i < EE) atomicAdd(&lh[dst[i] >> 6], 1);
    }
    __syncthreads();
    for (int j = tid; j < NBK; j += 256)
        if (lh[j] > 0) atomicAdd(&bcnt[j], lh[j]);
}

__global__ __launch_bounds__(256) void scan_p1_kernel(const int* __restrict__ cnt,
                                                      int* __restrict__ bsum, int n) {
    __shared__ int red[8];
    int i = blockIdx.x * 256 + threadIdx.x;
    int v = (i < n) ? cnt[i] : 0;
    for (int off = 32; off > 0; off >>= 1) v += __shfl_down(v, off, 64);
    int wv = threadIdx.x >> 6;
    if ((threadIdx.x & 63) == 0) red[wv] = v;
    __syncthreads();
    if (threadIdx.x == 0) bsum[blockIdx.x] = red[0] + red[1] + red[2] + red[3];
}

__global__ __launch_bounds__(1024) void scan_p2_kernel(int* __restrict__ bsum, int nb) {
    __shared__ int s[1024];
    int tid = threadIdx.x;
    int v = (tid < nb) ? bsum[tid] : 0;
    s[tid] = v;
    __syncthreads();
    for (int off = 1; off < 1024; off <<= 1) {
        int u = (tid >= off) ? s[tid - off] : 0;
        __syncthreads();
        s[tid] += u;
        __syncthreads();
    }
    if (tid < nb) bsum[tid] = s[tid] - v;
}

__global__ __launch_bounds__(256) void scan_p3_kernel(const int* __restrict__ cnt,
                                                      const int* __restrict__ bsum,
                                                      int* __restrict__ out_ptr, int n) {
    __shared__ int s[256];
    int tid = threadIdx.x;
    int i = blockIdx.x * 256 + tid;
    int v = (i < n) ? cnt[i] : 0;
    s[tid] = v;
    __syncthreads();
    for (int off = 1; off < 256; off <<= 1) {
        int u = (tid >= off) ? s[tid - off] : 0;
        __syncthreads();
        s[tid] += u;
        __syncthreads();
    }
    if (i < n) {
        int excl = bsum[blockIdx.x] + s[tid] - v;
        out_ptr[i] = excl;
        if (i == n - 1) out_ptr[n] = excl + v;
    }
}

__global__ __launch_bounds__(256) void bscatter_kernel(
    const int* __restrict__ src, const int* __restrict__ dst,
    const int* __restrict__ bptr, int* __restrict__ bfill, int* __restrict__ ebuf) {
    __shared__ int lh[NBK];
    __shared__ int lbase[NBK];
    int tid = threadIdx.x;
    for (int j = tid; j < NBK; j += 256) lh[j] = 0;
    __syncthreads();
    int e0 = blockIdx.x * EPB;
#pragma unroll
    for (int k = 0; k < EPB / 256; ++k) {
        int i = e0 + k * 256 + tid;
        if (i < EE) atomicAdd(&lh[dst[i] >> 6], 1);
    }
    __syncthreads();
    for (int j = tid; j < NBK; j += 256)
        if (lh[j] > 0) lbase[j] = atomicAdd(&bfill[j], lh[j]);
    __syncthreads();
    for (int j = tid; j < NBK; j += 256) lh[j] = 0;
    __syncthreads();
#pragma unroll
    for (int k = 0; k < EPB / 256; ++k) {
        int i = e0 + k * 256 + tid;
        if (i < EE) {
            int d = dst[i];
            int b = d >> 6;
            int off = atomicAdd(&lh[b], 1);
            ebuf[bptr[b] + lbase[b] + off] = (src[i] << 6) | (d & 63);
        }
    }
}

__global__ __launch_bounds__(256) void csr_build_kernel(
    const int* __restrict__ ebuf, const int* __restrict__ bptr,
    int* __restrict__ rowptr, int* __restrict__ colsrc,
    float* __restrict__ dinv, float* __restrict__ dinv2, float* __restrict__ sdeg) {
    __shared__ int pk[CAP];
    __shared__ int ob[CAP];
    __shared__ int cnt[64];
    __shared__ int sexcl[64];
    __shared__ int fill[64];

    int tid = threadIdx.x;
    int b = blockIdx.x;
    int start = bptr[b];
    int cb = bptr[b + 1] - start;
    if (cb > CAP) cb = CAP;

    if (tid < 64) { cnt[tid] = 0; fill[tid] = 0; }
    __syncthreads();

    for (int i = tid; i < cb; i += 256) {
        int v = ebuf[start + i];
        pk[i] = v;
        atomicAdd(&cnt[v & 63], 1);
    }
    __syncthreads();

    if (tid < 64) {
        int v = cnt[tid];
        int inc = v;
        for (int off = 1; off < 64; off <<= 1) {
            int u = __shfl_up(inc, off, 64);
            if (tid >= off) inc += u;
        }
        int excl = inc - v;
        sexcl[tid] = excl;
        int gnode = b * 64 + tid;
        if (gnode < NN) {
            rowptr[gnode] = start + excl;
            int d = v < 1 ? 1 : v;
            float fd = (float)d;
            dinv[gnode]  = 1.0f / sqrtf(fd);
            dinv2[gnode] = 1.0f / fd;
            sdeg[gnode]  = sqrtf(fd);
        }
    }
    if (b == 0 && tid == 0) rowptr[NN] = EE;
    __syncthreads();

    for (int i = tid; i < cb; i += 256) {
        int v = pk[i];
        int d = v & 63;
        int off = atomicAdd(&fill[d], 1);
        ob[sexcl[d] + off] = v >> 6;
    }
    __syncthreads();

    for (int i = tid; i < cb; i += 256) colsrc[start + i] = ob[i];
}

// ---------------- W precompute: [layer][ncol(128)][k(384)] fp16 ----------------

__global__ __launch_bounds__(256) void wprep_kernel(
    const float* __restrict__ W0, const float* __restrict__ Wh, const float* __restrict__ Wl,
    _Float16* __restrict__ Wh16)
{
    int idx = blockIdx.x * 256 + threadIdx.x;
    const int PER = 128 * 384;
    if (idx >= 7 * PER) return;
    int layer = idx / PER;
    int rem = idx - layer * PER;
    int ncol = rem / 384;
    int k = rem - ncol * 384;
    const float* W; int outc;
    if (layer == 0)      { W = W0; outc = 128; }
    else if (layer < 6)  { W = Wh + (size_t)(layer - 1) * 384 * 128; outc = 128; }
    else                 { W = Wl; outc = 40; }
    float v = (ncol < outc) ? W[(size_t)k * outc + ncol] : 0.f;
    Wh16[idx] = (_Float16)v;
}

// ---------------- feature convert: Z0 = dinv .* X, fp16 ----------------

__global__ __launch_bounds__(256) void fcvt_kernel(const float* __restrict__ in,
                                                   const float* __restrict__ dinv,
                                                   _Float16* __restrict__ out, int total4) {
    int i = blockIdx.x * 256 + threadIdx.x;
    if (i >= total4) return;
    int node = i >> 5;
    float dv = dinv[node];
    floatx4 v = *(const floatx4*)&in[i * 4];
    half4_t r = { (_Float16)(dv * v.x), (_Float16)(dv * v.y),
                  (_Float16)(dv * v.z), (_Float16)(dv * v.w) };
    *(half4_t*)&out[i * 4] = r;
}

// ---------------- SpMM (Z-space, pure gather-sum, LINEAR node order) ----------------
// Zout[d] = alpha*dinv2[d]*sum_e Zin[src] + beta*Zo[d]

__global__ __launch_bounds__(256) void spmm_h_kernel(
    _Float16* __restrict__ out, const _Float16* __restrict__ Xin,
    const _Float16* __restrict__ Xo, const float* __restrict__ dinv2,
    const int* __restrict__ rp, const int* __restrict__ cs,
    float alpha, float beta, int n)
{
    int slot = threadIdx.x >> 4;
    int lane = threadIdx.x & 15;
    int node = blockIdx.x * 16 + slot;
    if (node >= n) return;
    const half8_t* X8 = (const half8_t*)Xin;
    float acc[8] = { 0.f, 0.f, 0.f, 0.f, 0.f, 0.f, 0.f, 0.f };
    int s = rp[node], e = rp[node + 1];
    int i = s;
    for (; i + 8 <= e; i += 8) {
        int idx[8];
#pragma unroll
        for (int u = 0; u < 8; ++u) idx[u] = cs[i + u];
        half8_t x[8];
#pragma unroll
        for (int u = 0; u < 8; ++u) x[u] = X8[(size_t)idx[u] * 16 + lane];
#pragma unroll
        for (int u = 0; u < 8; ++u)
#pragma unroll
            for (int j = 0; j < 8; ++j) acc[j] += (float)x[u][j];
    }
    for (; i < e; ++i) {
        int sidx = cs[i];
        half8_t x = X8[(size_t)sidx * 16 + lane];
#pragma unroll
        for (int j = 0; j < 8; ++j) acc[j] += (float)x[j];
    }
    float sc = alpha * dinv2[node];
    half8_t r;
    if (beta != 0.f) {
        half8_t o = ((const half8_t*)Xo)[(size_t)node * 16 + lane];
#pragma unroll
        for (int j = 0; j < 8; ++j) r[j] = (_Float16)(sc * acc[j] + beta * (float)o[j]);
    } else {
#pragma unroll
        for (int j = 0; j < 8; ++j) r[j] = (_Float16)(sc * acc[j]);
    }
    ((half8_t*)out)[(size_t)node * 16 + lane] = r;
}

// ---------------- GEMM: pure fp16 MFMA, LDS W-slab, row scale in epilogue ----------------
// acc = Z·W. Hidden: store relu(acc + dinv*b) fp16 (Z-space directly).
// Last: store relu(sdeg*acc + b) fp32.

template <int OUTC, int NT, bool HOUT>
__global__ __launch_bounds__(256, 4) void gemm_f16_kernel(
    void* __restrict__ outp, const _Float16* __restrict__ X0,
    const _Float16* __restrict__ X1, const _Float16* __restrict__ X2,
    const _Float16* __restrict__ Wh16, const float* __restrict__ bias,
    const float* __restrict__ sdeg, const float* __restrict__ dinv, int n)
{
    __shared__ _Float16 Ws[NT * 16][136];

    int tid = threadIdx.x;
    int lane = tid & 63;
    int wave = tid >> 6;
    int m15 = lane & 15;
    int quad = lane >> 4;
    int row0 = blockIdx.x * 128 + wave * 32;

    accfrag acc[2][NT];
#pragma unroll
    for (int mi = 0; mi < 2; ++mi)
#pragma unroll
        for (int nj = 0; nj < NT; ++nj) acc[mi][nj] = (accfrag){0.f, 0.f, 0.f, 0.f};

    int r0 = row0 + m15;
    int r1 = r0 + 16;
    size_t ro0 = (size_t)((r0 < n) ? r0 : 0) * 16;   // half8 units; OOB rows read
    size_t ro1 = (size_t)((r1 < n) ? r1 : 0) * 16;   // row 0, results never stored

    const _Float16* srcs[3] = { X0, X1, X2 };

    for (int sb = 0; sb < 3; ++sb) {
        // stage W slab: NT*16 rows x 128 fp16 (contiguous copy, coalesced)
        {
            const int VEC = NT * 256;          // half8 units
#pragma unroll
            for (int v0 = 0; v0 < VEC; v0 += 256) {
                int v = v0 + tid;
                int row = v >> 4;
                int c8 = (v & 15) * 8;
                *(half8_t*)&Ws[row][c8] =
                    *(const half8_t*)(Wh16 + (size_t)row * 384 + sb * 128 + c8);
            }
        }
        __syncthreads();

        const half8_t* Xp8 = (const half8_t*)srcs[sb];
#pragma unroll
        for (int kk = 0; kk < 4; ++kk) {
            int k0 = kk * 32 + quad * 8;
            half8_t a0 = Xp8[ro0 + kk * 4 + quad];
            half8_t a1 = Xp8[ro1 + kk * 4 + quad];
#pragma unroll
            for (int nj = 0; nj < NT; ++nj) {
                half8_t bfr = *(const half8_t*)&Ws[nj * 16 + m15][k0];
                acc[0][nj] = __builtin_amdgcn_mfma_f32_16x16x32_f16(a0, bfr, acc[0][nj], 0, 0, 0);
                acc[1][nj] = __builtin_amdgcn_mfma_f32_16x16x32_f16(a1, bfr, acc[1][nj], 0, 0, 0);
            }
        }
        __syncthreads();
    }

    // epilogue. C/D: col=lane&15, row=quad*4+reg.
    float rs[2][4];
#pragma unroll
    for (int mi = 0; mi < 2; ++mi)
#pragma unroll
        for (int reg = 0; reg < 4; ++reg) {
            int gr = row0 + mi * 16 + quad * 4 + reg;
            int cg = (gr < n) ? gr : 0;
            rs[mi][reg] = HOUT ? dinv[cg] : sdeg[cg];
        }
#pragma unroll
    for (int nj = 0; nj < NT; ++nj) {
        int col = nj * 16 + m15;
        float bv = (col < OUTC) ? bias[col] : 0.f;
#pragma unroll
        for (int mi = 0; mi < 2; ++mi) {
#pragma unroll
            for (int reg = 0; reg < 4; ++reg) {
                int gr = row0 + mi * 16 + quad * 4 + reg;
                if (gr < n && col < OUTC) {
                    if (HOUT) {
                        float v = acc[mi][nj][reg] + rs[mi][reg] * bv;
                        v = v > 0.f ? v : 0.f;
                        ((_Float16*)outp)[(size_t)gr * OUTC + col] = (_Float16)v;
                    } else {
                        float v = rs[mi][reg] * acc[mi][nj][reg] + bv;
                        v = v > 0.f ? v : 0.f;
                        ((float*)outp)[(size_t)gr * OUTC + col] = v;
                    }
                }
            }
        }
    }
}

// ---------------- launch ----------------

extern "C" void kernel_launch(void* const* d_in, const int* in_sizes, int n_in,
                              void* d_out, int out_size, void* d_ws, size_t ws_size,
                              hipStream_t stream) {
    const float* features = (const float*)d_in[0];
    const int*   src      = (const int*)d_in[1];
    const int*   dst      = (const int*)d_in[2];
    const float* W0       = (const float*)d_in[3];
    const float* b0       = (const float*)d_in[4];
    const float* Wh       = (const float*)d_in[5];
    const float* bh       = (const float*)d_in[6];
    const float* Wl       = (const float*)d_in[7];
    const float* bl       = (const float*)d_in[8];
    float* out = (float*)d_out;

    const int N = NN, E = EE;
    const int WTOT = 7 * 128 * 384;
    const int EB = (E + EPB - 1) / EPB;
    const int NB2 = (NBK + 255) / 256;

    char* ws = (char*)d_ws;
    size_t off = 0;
    auto alloc = [&](size_t bytes) -> void* {
        void* p = ws + off;
        off += (bytes + 511) & ~(size_t)511;
        return p;
    };
    int*      bcnt   = (int*)alloc((size_t)NBK * 4);
    int*      bfill  = (int*)alloc((size_t)NBK * 4);
    int*      bptr   = (int*)alloc((size_t)(NBK + 1) * 4);
    int*      bsum   = (int*)alloc((size_t)NB2 * 4);
    int*      rowptr = (int*)alloc((size_t)(N + 1) * 4);
    int*      ebuf   = (int*)alloc((size_t)E * 4);
    int*      colsrc = (int*)alloc((size_t)E * 4);
    float*    dinv   = (float*)alloc((size_t)N * 4);
    float*    dinv2  = (float*)alloc((size_t)N * 4);
    float*    sdeg   = (float*)alloc((size_t)N * 4);
    _Float16* Wh16   = (_Float16*)alloc((size_t)WTOT * 2);
    _Float16* XA     = (_Float16*)alloc((size_t)N * FF * 2);
    _Float16* XB     = (_Float16*)alloc((size_t)N * FF * 2);
    _Float16* B1     = (_Float16*)alloc((size_t)N * FF * 2);
    _Float16* B2     = (_Float16*)alloc((size_t)N * FF * 2);

    // bucketed CSR build
    hipMemsetAsync(bcnt, 0, (size_t)NBK * 4, stream);
    hipMemsetAsync(bfill, 0, (size_t)NBK * 4, stream);
    bhist_kernel<<<EB, 256, 0, stream>>>(dst, bcnt);
    wprep_kernel<<<(WTOT + 255) / 256, 256, 0, stream>>>(W0, Wh, Wl, Wh16);
    scan_p1_kernel<<<NB2, 256, 0, stream>>>(bcnt, bsum, NBK);
    scan_p2_kernel<<<1, 1024, 0, stream>>>(bsum, NB2);
    scan_p3_kernel<<<NB2, 256, 0, stream>>>(bcnt, bsum, bptr, NBK);
    bscatter_kernel<<<EB, 256, 0, stream>>>(src, dst, bptr, bfill, ebuf);
    csr_build_kernel<<<NBK, 256, 0, stream>>>(ebuf, bptr, rowptr, colsrc, dinv, dinv2, sdeg);
    fcvt_kernel<<<(N * FF / 4 + 255) / 256, 256, 0, stream>>>(features, dinv, XA, N * FF / 4);

    const _Float16* cur = XA;
    _Float16* nxt = XB;
    int spmm_grid = (N + 15) / 16;
    int gemm_grid = (N + 127) / 128;

    for (int layer = 0; layer < 7; ++layer) {
        const float* b;
        bool last = (layer == 6);
        if (layer == 0)      { b = b0; }
        else if (layer < 6)  { b = bh + (layer - 1) * 128; }
        else                 { b = bl; }
        const _Float16* wl16 = Wh16 + (size_t)layer * 128 * 384;

        spmm_h_kernel<<<spmm_grid, 256, 0, stream>>>(B1, cur, cur, dinv2, rowptr, colsrc, -1.f, 0.f, N);
        spmm_h_kernel<<<spmm_grid, 256, 0, stream>>>(B2, B1, cur, dinv2, rowptr, colsrc, -2.f, -1.f, N);

        if (!last)
            gemm_f16_kernel<128, 8, true><<<gemm_grid, 256, 0, stream>>>(
                (void*)nxt, cur, B1, B2, wl16, b, sdeg, dinv, N);
        else
            gemm_f16_kernel<40, 3, false><<<gemm_grid, 256, 0, stream>>>(
                (void*)out, cur, B1, B2, wl16, b, sdeg, dinv, N);

        if (layer < 6) {
            const _Float16* newcur = nxt;
            nxt = (_Float16*)((nxt == XB) ? XA : XB);
            cur = newcur;
        }
    }
}